// Round 9
// baseline (374.014 us; speedup 1.0000x reference)
//
#include <hip/hip_runtime.h>
#include <math.h>

// BridgeNodes R9 (= R8 with compile fix): non-temporal epilogue stores via
// native clang ext-vector (HIP float4 class type is rejected by
// __builtin_nontemporal_store), 5 blocks/CU, write-contiguous grid order,
// vectorized split. bf16 MFMA + threshold-band exact-fixup numerics unchanged.

constexpr int GROUPS = 4;
constexpr int N = 4096;
constexpr int F = 128;
constexpr int BT = 128;
constexpr int TILES = N / BT;                    // 32
constexpr float THRESH = 0.6f;
constexpr float LOGIT = 0.405465108f;            // ln(1.5)
constexpr float BAND = 0.006f;                   // >> max bf16 dot error

constexpr size_t H_OFF_SHORTS = 8;               // counter occupies 16 B of ws
constexpr size_t H_ELEMS = (size_t)GROUPS * N * F;

using short8 = __attribute__((ext_vector_type(8))) short;
using short4v = __attribute__((ext_vector_type(4))) short;
using f32x4  = __attribute__((ext_vector_type(4))) float;

__device__ __forceinline__ short f2bf_rne(float x) {
    unsigned u = __float_as_uint(x);
    return (short)((u + 0x7FFFu + ((u >> 16) & 1u)) >> 16);
}

__global__ void split_kernel(const float* __restrict__ in, short* __restrict__ h,
                             unsigned* __restrict__ cnt) {
    const int i = blockIdx.x * 256 + threadIdx.x;   // float4 index
    if (i == 0) *cnt = 0;                        // ws is re-poisoned each launch
    if ((size_t)i * 4 < H_ELEMS) {
        const f32x4 x = *((const f32x4*)in + i);
        short4v s;
        s.x = f2bf_rne(x.x); s.y = f2bf_rne(x.y);
        s.z = f2bf_rne(x.z); s.w = f2bf_rne(x.w);
        *((short4v*)h + i) = s;
    }
}

#define GLL16(gp, lp)                                                        \
    __builtin_amdgcn_global_load_lds(                                        \
        (const __attribute__((address_space(1))) void*)(gp),                 \
        (__attribute__((address_space(3))) void*)(lp), 16, 0, 0)

__global__ __launch_bounds__(256, 5)
void bridge_mfma_kernel(const short* __restrict__ W, float* __restrict__ out,
                        unsigned* __restrict__ cnt, unsigned* __restrict__ list,
                        unsigned cap) {
    __shared__ alignas(16) short ldsA[BT * 64];  // 16 KB (half-K)
    __shared__ alignas(16) short ldsB[BT * 64];  // 16 KB

    const int g  = blockIdx.y;
    const int bm = blockIdx.x & 31;              // FAST axis: A tile = out col
    const int bn = blockIdx.x >> 5;              // slow axis: B tile = out row
    // consecutive blocks write adjacent 512B col segments of the same rows

    const int tid  = threadIdx.x;
    const int lane = tid & 63;
    const int wv   = tid >> 6;
    const int lm   = lane & 15;
    const int q    = lane >> 4;
    const int R    = (wv & 1) * 64;              // A quadrant
    const int C    = (wv >> 1) * 64;             // B quadrant

    const short* baseA = W + ((size_t)g * N + bm * BT) * F;
    const short* baseB = W + ((size_t)g * N + bn * BT) * F;

    f32x4 acc[4][4] = {};

#pragma unroll
    for (int kh = 0; kh < 2; ++kh) {             // two 64-k halves
        if (kh) __syncthreads();                 // prior half's frags consumed
        const int ko = kh * 64;
#pragma unroll
        for (int it = 0; it < 4; ++it) {
            const int g0 = tid + 256 * it;       // granule 0..1023
            const int r  = g0 >> 3;              // row 0..127
            const int o  = g0 & 7;               // octet slot 0..7
            const int so = o ^ (r & 7);          // XOR swizzle (conflict-free)
            GLL16(baseA + (size_t)r * F + ko + so * 8, &ldsA[g0 * 8]);
            GLL16(baseB + (size_t)r * F + ko + so * 8, &ldsB[g0 * 8]);
        }
        __syncthreads();

#pragma unroll
        for (int kcl = 0; kcl < 2; ++kcl) {      // two K=32 MFMA steps per half
            const int oc = kcl * 4 + q;
            short8 af[4], bf[4];
#pragma unroll
            for (int i = 0; i < 4; ++i) {
                const int row = R + i * 16 + lm;
                af[i] = *(const short8*)(ldsA + row * 64 + ((oc ^ (lm & 7)) * 8));
            }
#pragma unroll
            for (int j = 0; j < 4; ++j) {
                const int row = C + j * 16 + lm;
                bf[j] = *(const short8*)(ldsB + row * 64 + ((oc ^ (lm & 7)) * 8));
            }
#pragma unroll
            for (int i = 0; i < 4; ++i)
#pragma unroll
                for (int j = 0; j < 4; ++j)
                    acc[i][j] = __builtin_amdgcn_mfma_f32_16x16x32_bf16(
                        af[i], bf[j], acc[i][j], 0, 0, 0);
        }
    }

    __syncthreads();                             // frags consumed
    unsigned* sc = (unsigned*)ldsA;              // sc[0]=blkCnt, sc[1]=blkBase
    if (tid == 0) sc[0] = 0;
    __syncthreads();

    // ---- epilogue per j: sigmoid + threshold + band flags, NT f32x4 store ----
    // acc[i][j][r] = dot(A-row bm*BT+R+i*16+q*4+r, B-row bn*BT+C+j*16+lm).
    // Store at out[(B-row)][(A-row)] (dot symmetric; each tile written once).
    const size_t outg = (size_t)g * N * N;
    unsigned local[8];
    int nf = 0;
#pragma unroll
    for (int j = 0; j < 4; ++j) {
        const unsigned orow = bn * BT + C + j * 16 + lm;
        float* o = out + outg + (size_t)orow * N + bm * BT + R;
        float v[4][4];
#pragma unroll
        for (int i = 0; i < 4; ++i)
#pragma unroll
            for (int r = 0; r < 4; ++r) {
                const float x = acc[i][j][r];
                const float e = __expf(-x);
                const float s = __builtin_amdgcn_rcpf(1.0f + e);
                v[i][r] = (s < THRESH) ? 0.0f : s;
                if (fabsf(x - LOGIT) < BAND) {
                    const unsigned ocol = bm * BT + R + i * 16 + q * 4 + r;
                    const unsigned enc = ((unsigned)g << 24) | (orow << 12) | ocol;
                    if (nf < 8) local[nf++] = enc;
                    else {                       // statistically never
                        const unsigned idx = atomicAdd(cnt, 1u);
                        if (idx < cap) list[idx] = enc;
                    }
                }
            }
#pragma unroll
        for (int i = 0; i < 4; ++i) {
            f32x4 t = {v[i][0], v[i][1], v[i][2], v[i][3]};
            __builtin_nontemporal_store(t, (f32x4*)(o + i * 16 + q * 4));
        }
    }

    // ---- block-aggregated flag publication: ONE global atomic per block ----
    __syncthreads();
    unsigned myoff = 0;
    if (nf) myoff = atomicAdd(&sc[0], (unsigned)nf);
    __syncthreads();
    if (tid == 0) sc[1] = sc[0] ? atomicAdd(cnt, sc[0]) : 0u;
    __syncthreads();
    if (nf) {
        const unsigned base = sc[1] + myoff;
        for (int k = 0; k < nf; ++k)
            if (base + k < cap) list[base + k] = local[k];
    }
}

// ---- exact recompute of flagged entries: sequential fp32 fmaf + expf ----
__global__ void fixup_kernel(const float* __restrict__ nodes, float* __restrict__ out,
                             const unsigned* __restrict__ cnt,
                             const unsigned* __restrict__ list, unsigned cap) {
    unsigned n = *cnt;
    if (n > cap) n = cap;
    const unsigned stride = gridDim.x * blockDim.x;
    for (unsigned idx = blockIdx.x * blockDim.x + threadIdx.x; idx < n; idx += stride) {
        const unsigned p = list[idx];
        const unsigned g = p >> 24, row = (p >> 12) & 0xFFF, col = p & 0xFFF;
        const float* a = nodes + ((size_t)g * N + row) * F;
        const float* b = nodes + ((size_t)g * N + col) * F;
        float acc = 0.0f;
        for (int k = 0; k < F; ++k)              // sequential ascending-k == np
            acc = fmaf(a[k], b[k], acc);
        const float s = 1.0f / (1.0f + expf(-acc));
        const float v = (s < THRESH) ? 0.0f : s;
        out[(size_t)g * N * N + (size_t)row * N + col] = v;
        out[(size_t)g * N * N + (size_t)col * N + row] = v;
    }
}

extern "C" void kernel_launch(void* const* d_in, const int* in_sizes, int n_in,
                              void* d_out, int out_size, void* d_ws, size_t ws_size,
                              hipStream_t stream) {
    const float* nodes = (const float*)d_in[0];
    float* out = (float*)d_out;

    unsigned* cnt = (unsigned*)d_ws;
    short* h = (short*)d_ws + H_OFF_SHORTS;
    const size_t list_off_bytes = 16 + H_ELEMS * sizeof(short);
    unsigned* list = (unsigned*)((char*)d_ws + list_off_bytes);
    const size_t cap_sz = (ws_size > list_off_bytes + 16)
                              ? (ws_size - list_off_bytes) / sizeof(unsigned) : 0;
    const unsigned cap = (unsigned)(cap_sz > (1u << 22) ? (1u << 22) : cap_sz);

    split_kernel<<<(int)((H_ELEMS / 4 + 255) / 256), 256, 0, stream>>>(nodes, h, cnt);

    dim3 grid(TILES * TILES, GROUPS);            // 1024 x 4 = 4096 blocks
    bridge_mfma_kernel<<<grid, 256, 0, stream>>>(h, out, cnt, list, cap);

    fixup_kernel<<<512, 256, 0, stream>>>(nodes, out, cnt, list, cap);
}

// Round 10
// 339.503 us; speedup vs baseline: 1.1017x; 1.1017x over previous
//
#include <hip/hip_runtime.h>
#include <math.h>

// BridgeNodes R10: revert R9's NT store + bounds(256,5) (regression: NT
// bypasses L2 write-combining and the post-store barrier exposed the drain).
// Keep R7 config (plain f32x4 stores, bounds(256,4), bm-fast grid). New:
//  (1) band flags published BEFORE the store burst -> no barrier after
//      stores, waves retire with stores in flight;
//  (2) flag only orow<=ocol (twin block covers mirror) -> fixup work halved.
// bf16 MFMA + threshold-band exact-fixup numerics unchanged (R5-R9 proven).

constexpr int GROUPS = 4;
constexpr int N = 4096;
constexpr int F = 128;
constexpr int BT = 128;
constexpr int TILES = N / BT;                    // 32
constexpr float THRESH = 0.6f;
constexpr float LOGIT = 0.405465108f;            // ln(1.5)
constexpr float BAND = 0.006f;                   // >> max bf16 dot error

constexpr size_t H_OFF_SHORTS = 8;               // counter occupies 16 B of ws
constexpr size_t H_ELEMS = (size_t)GROUPS * N * F;

using short8  = __attribute__((ext_vector_type(8))) short;
using short4v = __attribute__((ext_vector_type(4))) short;
using f32x4   = __attribute__((ext_vector_type(4))) float;

__device__ __forceinline__ short f2bf_rne(float x) {
    unsigned u = __float_as_uint(x);
    return (short)((u + 0x7FFFu + ((u >> 16) & 1u)) >> 16);
}

__global__ void split_kernel(const float* __restrict__ in, short* __restrict__ h,
                             unsigned* __restrict__ cnt) {
    const int i = blockIdx.x * 256 + threadIdx.x;   // float4 index
    if (i == 0) *cnt = 0;                        // ws is re-poisoned each launch
    if ((size_t)i * 4 < H_ELEMS) {
        const f32x4 x = *((const f32x4*)in + i);
        short4v s;
        s.x = f2bf_rne(x.x); s.y = f2bf_rne(x.y);
        s.z = f2bf_rne(x.z); s.w = f2bf_rne(x.w);
        *((short4v*)h + i) = s;
    }
}

#define GLL16(gp, lp)                                                        \
    __builtin_amdgcn_global_load_lds(                                        \
        (const __attribute__((address_space(1))) void*)(gp),                 \
        (__attribute__((address_space(3))) void*)(lp), 16, 0, 0)

__global__ __launch_bounds__(256, 4)
void bridge_mfma_kernel(const short* __restrict__ W, float* __restrict__ out,
                        unsigned* __restrict__ cnt, unsigned* __restrict__ list,
                        unsigned cap) {
    __shared__ alignas(16) short ldsA[BT * 64];  // 16 KB (half-K)
    __shared__ alignas(16) short ldsB[BT * 64];  // 16 KB

    const int g  = blockIdx.y;
    const int bm = blockIdx.x & 31;              // FAST axis: A tile = out col
    const int bn = blockIdx.x >> 5;              // slow axis: B tile = out row

    const int tid  = threadIdx.x;
    const int lane = tid & 63;
    const int wv   = tid >> 6;
    const int lm   = lane & 15;
    const int q    = lane >> 4;
    const int R    = (wv & 1) * 64;              // A quadrant
    const int C    = (wv >> 1) * 64;             // B quadrant

    const short* baseA = W + ((size_t)g * N + bm * BT) * F;
    const short* baseB = W + ((size_t)g * N + bn * BT) * F;

    f32x4 acc[4][4] = {};

#pragma unroll
    for (int kh = 0; kh < 2; ++kh) {             // two 64-k halves
        if (kh) __syncthreads();                 // prior half's frags consumed
        const int ko = kh * 64;
#pragma unroll
        for (int it = 0; it < 4; ++it) {
            const int g0 = tid + 256 * it;       // granule 0..1023
            const int r  = g0 >> 3;              // row 0..127
            const int o  = g0 & 7;               // octet slot 0..7
            const int so = o ^ (r & 7);          // XOR swizzle (conflict-free)
            GLL16(baseA + (size_t)r * F + ko + so * 8, &ldsA[g0 * 8]);
            GLL16(baseB + (size_t)r * F + ko + so * 8, &ldsB[g0 * 8]);
        }
        __syncthreads();

#pragma unroll
        for (int kcl = 0; kcl < 2; ++kcl) {      // two K=32 MFMA steps per half
            const int oc = kcl * 4 + q;
            short8 af[4], bf[4];
#pragma unroll
            for (int i = 0; i < 4; ++i) {
                const int row = R + i * 16 + lm;
                af[i] = *(const short8*)(ldsA + row * 64 + ((oc ^ (lm & 7)) * 8));
            }
#pragma unroll
            for (int j = 0; j < 4; ++j) {
                const int row = C + j * 16 + lm;
                bf[j] = *(const short8*)(ldsB + row * 64 + ((oc ^ (lm & 7)) * 8));
            }
#pragma unroll
            for (int i = 0; i < 4; ++i)
#pragma unroll
                for (int j = 0; j < 4; ++j)
                    acc[i][j] = __builtin_amdgcn_mfma_f32_16x16x32_bf16(
                        af[i], bf[j], acc[i][j], 0, 0, 0);
        }
    }

    __syncthreads();                             // frags consumed
    unsigned* sc = (unsigned*)ldsA;              // sc[0]=blkCnt, sc[1]=blkBase
    if (tid == 0) sc[0] = 0;
    __syncthreads();

    // ---- pass 1: band flags from raw acc (cheap: sub+abs+cmp), orow<=ocol ----
    // acc[i][j][r] = dot(A-row bm*BT+R+i*16+q*4+r, B-row bn*BT+C+j*16+lm);
    // this block stores it at out[orow=B-row][ocol=A-row].
    unsigned local[8];
    int nf = 0;
#pragma unroll
    for (int j = 0; j < 4; ++j) {
        const unsigned orow = bn * BT + C + j * 16 + lm;
#pragma unroll
        for (int i = 0; i < 4; ++i) {
            const unsigned ocol0 = bm * BT + R + i * 16 + q * 4;
#pragma unroll
            for (int r = 0; r < 4; ++r) {
                const float x = acc[i][j][r];
                if (fabsf(x - LOGIT) < BAND) {
                    const unsigned ocol = ocol0 + r;
                    if (orow <= ocol) {          // twin block flags the mirror
                        const unsigned enc = ((unsigned)g << 24) | (orow << 12) | ocol;
                        if (nf < 8) local[nf++] = enc;
                        else {                   // statistically never
                            const unsigned idx = atomicAdd(cnt, 1u);
                            if (idx < cap) list[idx] = enc;
                        }
                    }
                }
            }
        }
    }

    // ---- publish flags: ONE global atomic per block (before any stores) ----
    unsigned myoff = 0;
    if (nf) myoff = atomicAdd(&sc[0], (unsigned)nf);
    __syncthreads();
    if (tid == 0) sc[1] = sc[0] ? atomicAdd(cnt, sc[0]) : 0u;
    __syncthreads();
    if (nf) {
        const unsigned base = sc[1] + myoff;
        for (int k = 0; k < nf; ++k)
            if (base + k < cap) list[base + k] = local[k];
    }

    // ---- pass 2: sigmoid + threshold + store burst (LAST — no barrier after) ----
    const size_t outg = (size_t)g * N * N;
#pragma unroll
    for (int j = 0; j < 4; ++j) {
        const unsigned orow = bn * BT + C + j * 16 + lm;
        float* o = out + outg + (size_t)orow * N + bm * BT + R;
#pragma unroll
        for (int i = 0; i < 4; ++i) {
            f32x4 t;
#pragma unroll
            for (int r = 0; r < 4; ++r) {
                const float x = acc[i][j][r];
                const float e = __expf(-x);
                const float s = __builtin_amdgcn_rcpf(1.0f + e);
                t[r] = (s < THRESH) ? 0.0f : s;
            }
            *(f32x4*)(o + i * 16 + q * 4) = t;
        }
    }
}

// ---- exact recompute of flagged entries: sequential fp32 fmaf + expf ----
__global__ void fixup_kernel(const float* __restrict__ nodes, float* __restrict__ out,
                             const unsigned* __restrict__ cnt,
                             const unsigned* __restrict__ list, unsigned cap) {
    unsigned n = *cnt;
    if (n > cap) n = cap;
    const unsigned stride = gridDim.x * blockDim.x;
    for (unsigned idx = blockIdx.x * blockDim.x + threadIdx.x; idx < n; idx += stride) {
        const unsigned p = list[idx];
        const unsigned g = p >> 24, row = (p >> 12) & 0xFFF, col = p & 0xFFF;
        const float* a = nodes + ((size_t)g * N + row) * F;
        const float* b = nodes + ((size_t)g * N + col) * F;
        float acc = 0.0f;
        for (int k = 0; k < F; ++k)              // sequential ascending-k == np
            acc = fmaf(a[k], b[k], acc);
        const float s = 1.0f / (1.0f + expf(-acc));
        const float v = (s < THRESH) ? 0.0f : s;
        out[(size_t)g * N * N + (size_t)row * N + col] = v;
        out[(size_t)g * N * N + (size_t)col * N + row] = v;   // mirror twin
    }
}

extern "C" void kernel_launch(void* const* d_in, const int* in_sizes, int n_in,
                              void* d_out, int out_size, void* d_ws, size_t ws_size,
                              hipStream_t stream) {
    const float* nodes = (const float*)d_in[0];
    float* out = (float*)d_out;

    unsigned* cnt = (unsigned*)d_ws;
    short* h = (short*)d_ws + H_OFF_SHORTS;
    const size_t list_off_bytes = 16 + H_ELEMS * sizeof(short);
    unsigned* list = (unsigned*)((char*)d_ws + list_off_bytes);
    const size_t cap_sz = (ws_size > list_off_bytes + 16)
                              ? (ws_size - list_off_bytes) / sizeof(unsigned) : 0;
    const unsigned cap = (unsigned)(cap_sz > (1u << 22) ? (1u << 22) : cap_sz);

    split_kernel<<<(int)((H_ELEMS / 4 + 255) / 256), 256, 0, stream>>>(nodes, h, cnt);

    dim3 grid(TILES * TILES, GROUPS);            // 1024 x 4 = 4096 blocks
    bridge_mfma_kernel<<<grid, 256, 0, stream>>>(h, out, cnt, list, cap);

    fixup_kernel<<<512, 256, 0, stream>>>(nodes, out, cnt, list, cap);
}

// Round 11
// 317.103 us; speedup vs baseline: 1.1795x; 1.0706x over previous
//
#include <hip/hip_runtime.h>
#include <math.h>

// BridgeNodes R11: R10 + LDS-transposed epilogue. MFMA C/D layout makes
// direct stores write 16 scattered 64B lines per inst (16 rows, 16KB stride);
// re-tiling through LDS (reusing the 32KB staging buffers, XOR-swizzled
// 16B granules) makes each store inst write two contiguous 512B row
// segments — 8x contiguity, matching the harness fill's access shape.
// Staging/MFMA/flags/fixup numerics unchanged (R5-R10 proven).

constexpr int GROUPS = 4;
constexpr int N = 4096;
constexpr int F = 128;
constexpr int BT = 128;
constexpr int TILES = N / BT;                    // 32
constexpr float THRESH = 0.6f;
constexpr float LOGIT = 0.405465108f;            // ln(1.5)
constexpr float BAND = 0.006f;                   // >> max bf16 dot error

constexpr size_t H_OFF_SHORTS = 8;               // counter occupies 16 B of ws
constexpr size_t H_ELEMS = (size_t)GROUPS * N * F;

using short8  = __attribute__((ext_vector_type(8))) short;
using short4v = __attribute__((ext_vector_type(4))) short;
using f32x4   = __attribute__((ext_vector_type(4))) float;

__device__ __forceinline__ short f2bf_rne(float x) {
    unsigned u = __float_as_uint(x);
    return (short)((u + 0x7FFFu + ((u >> 16) & 1u)) >> 16);
}

__global__ void split_kernel(const float* __restrict__ in, short* __restrict__ h,
                             unsigned* __restrict__ cnt) {
    const int i = blockIdx.x * 256 + threadIdx.x;   // float4 index
    if (i == 0) *cnt = 0;                        // ws is re-poisoned each launch
    if ((size_t)i * 4 < H_ELEMS) {
        const f32x4 x = *((const f32x4*)in + i);
        short4v s;
        s.x = f2bf_rne(x.x); s.y = f2bf_rne(x.y);
        s.z = f2bf_rne(x.z); s.w = f2bf_rne(x.w);
        *((short4v*)h + i) = s;
    }
}

#define GLL16(gp, lp)                                                        \
    __builtin_amdgcn_global_load_lds(                                        \
        (const __attribute__((address_space(1))) void*)(gp),                 \
        (__attribute__((address_space(3))) void*)(lp), 16, 0, 0)

__global__ __launch_bounds__(256, 4)
void bridge_mfma_kernel(const short* __restrict__ W, float* __restrict__ out,
                        unsigned* __restrict__ cnt, unsigned* __restrict__ list,
                        unsigned cap) {
    // One 32 KB block: staging (2 x 16 KB bf16) then reused as the fp32
    // transpose buffer (64 rows x 32 granules x 16 B).
    __shared__ union SM {
        struct { alignas(16) short A[BT * 64]; alignas(16) short B[BT * 64]; } s;
        float t[64 * 32 * 4];
    } sm;
    __shared__ unsigned sc[2];                   // blkCnt, blkBase

    const int g  = blockIdx.y;
    const int bm = blockIdx.x & 31;              // FAST axis: A tile = out col
    const int bn = blockIdx.x >> 5;              // slow axis: B tile = out row

    const int tid  = threadIdx.x;
    const int lane = tid & 63;
    const int wv   = tid >> 6;
    const int lm   = lane & 15;
    const int q    = lane >> 4;
    const int R    = (wv & 1) * 64;              // A quadrant (out cols)
    const int C    = (wv >> 1) * 64;             // B quadrant (out rows)

    const short* baseA = W + ((size_t)g * N + bm * BT) * F;
    const short* baseB = W + ((size_t)g * N + bn * BT) * F;

    f32x4 acc[4][4] = {};

#pragma unroll
    for (int kh = 0; kh < 2; ++kh) {             // two 64-k halves
        if (kh) __syncthreads();                 // prior half's frags consumed
        const int ko = kh * 64;
#pragma unroll
        for (int it = 0; it < 4; ++it) {
            const int g0 = tid + 256 * it;       // granule 0..1023
            const int r  = g0 >> 3;              // row 0..127
            const int o  = g0 & 7;               // octet slot 0..7
            const int so = o ^ (r & 7);          // XOR swizzle (conflict-free)
            GLL16(baseA + (size_t)r * F + ko + so * 8, &sm.s.A[g0 * 8]);
            GLL16(baseB + (size_t)r * F + ko + so * 8, &sm.s.B[g0 * 8]);
        }
        __syncthreads();

#pragma unroll
        for (int kcl = 0; kcl < 2; ++kcl) {      // two K=32 MFMA steps per half
            const int oc = kcl * 4 + q;
            short8 af[4], bf[4];
#pragma unroll
            for (int i = 0; i < 4; ++i) {
                const int row = R + i * 16 + lm;
                af[i] = *(const short8*)(sm.s.A + row * 64 + ((oc ^ (lm & 7)) * 8));
            }
#pragma unroll
            for (int j = 0; j < 4; ++j) {
                const int row = C + j * 16 + lm;
                bf[j] = *(const short8*)(sm.s.B + row * 64 + ((oc ^ (lm & 7)) * 8));
            }
#pragma unroll
            for (int i = 0; i < 4; ++i)
#pragma unroll
                for (int j = 0; j < 4; ++j)
                    acc[i][j] = __builtin_amdgcn_mfma_f32_16x16x32_bf16(
                        af[i], bf[j], acc[i][j], 0, 0, 0);
        }
    }

    __syncthreads();                             // frags consumed
    if (tid == 0) sc[0] = 0;
    __syncthreads();

    // ---- pass 1: band flags from raw acc (cheap), orow<=ocol only ----
    // acc[i][j][r] = dot(A-row bm*BT+R+i*16+q*4+r, B-row bn*BT+C+j*16+lm);
    // stored at out[orow=B-row][ocol=A-row].
    unsigned local[8];
    int nf = 0;
#pragma unroll
    for (int j = 0; j < 4; ++j) {
        const unsigned orow = bn * BT + C + j * 16 + lm;
#pragma unroll
        for (int i = 0; i < 4; ++i) {
            const unsigned ocol0 = bm * BT + R + i * 16 + q * 4;
#pragma unroll
            for (int r = 0; r < 4; ++r) {
                if (fabsf(acc[i][j][r] - LOGIT) < BAND) {
                    const unsigned ocol = ocol0 + r;
                    if (orow <= ocol) {          // twin block flags the mirror
                        const unsigned enc = ((unsigned)g << 24) | (orow << 12) | ocol;
                        if (nf < 8) local[nf++] = enc;
                        else {                   // statistically never
                            const unsigned idx = atomicAdd(cnt, 1u);
                            if (idx < cap) list[idx] = enc;
                        }
                    }
                }
            }
        }
    }

    // ---- publish flags: ONE global atomic per block ----
    unsigned myoff = 0;
    if (nf) myoff = atomicAdd(&sc[0], (unsigned)nf);
    __syncthreads();
    if (tid == 0) sc[1] = sc[0] ? atomicAdd(cnt, sc[0]) : 0u;
    __syncthreads();
    if (nf) {
        const unsigned base = sc[1] + myoff;
        for (int k = 0; k < nf; ++k)
            if (base + k < cap) list[base + k] = local[k];
    }

    // ---- pass 2: transpose-store epilogue, two 64-row windows ----
    const size_t outg = (size_t)g * N * N;
#pragma unroll
    for (int h = 0; h < 2; ++h) {
        __syncthreads();                         // prior window read / frag reuse done
        if ((wv >> 1) == h) {                    // waves whose C-half is this window
#pragma unroll
            for (int j = 0; j < 4; ++j) {
                const int rl = j * 16 + lm;      // row_local 0..63
#pragma unroll
                for (int i = 0; i < 4; ++i) {
                    f32x4 v;
#pragma unroll
                    for (int r = 0; r < 4; ++r) {
                        const float x = acc[i][j][r];
                        const float e = __expf(-x);
                        const float s = __builtin_amdgcn_rcpf(1.0f + e);
                        v[r] = (s < THRESH) ? 0.0f : s;
                    }
                    const int c    = (R >> 2) + i * 4 + q;     // true granule 0..31
                    const int slot = c ^ (rl & 31);            // XOR swizzle
                    *(f32x4*)&sm.t[(rl * 32 + slot) * 4] = v;
                }
            }
        }
        __syncthreads();
        // read back row-major: each inst stores two contiguous 512B segments
#pragma unroll
        for (int it = 0; it < 8; ++it) {
            const int idx = tid + 256 * it;      // 0..2047
            const int rl  = idx >> 5;            // row_local 0..63
            const int gc  = idx & 31;            // true granule col
            const int slot = gc ^ (rl & 31);
            const f32x4 v = *(const f32x4*)&sm.t[(rl * 32 + slot) * 4];
            const int orow = bn * BT + h * 64 + rl;
            *(f32x4*)(out + outg + (size_t)orow * N + bm * BT + gc * 4) = v;
        }
    }
}

// ---- exact recompute of flagged entries: sequential fp32 fmaf + expf ----
__global__ void fixup_kernel(const float* __restrict__ nodes, float* __restrict__ out,
                             const unsigned* __restrict__ cnt,
                             const unsigned* __restrict__ list, unsigned cap) {
    unsigned n = *cnt;
    if (n > cap) n = cap;
    const unsigned stride = gridDim.x * blockDim.x;
    for (unsigned idx = blockIdx.x * blockDim.x + threadIdx.x; idx < n; idx += stride) {
        const unsigned p = list[idx];
        const unsigned g = p >> 24, row = (p >> 12) & 0xFFF, col = p & 0xFFF;
        const float* a = nodes + ((size_t)g * N + row) * F;
        const float* b = nodes + ((size_t)g * N + col) * F;
        float acc = 0.0f;
        for (int k = 0; k < F; ++k)              // sequential ascending-k == np
            acc = fmaf(a[k], b[k], acc);
        const float s = 1.0f / (1.0f + expf(-acc));
        const float v = (s < THRESH) ? 0.0f : s;
        out[(size_t)g * N * N + (size_t)row * N + col] = v;
        out[(size_t)g * N * N + (size_t)col * N + row] = v;   // mirror twin
    }
}

extern "C" void kernel_launch(void* const* d_in, const int* in_sizes, int n_in,
                              void* d_out, int out_size, void* d_ws, size_t ws_size,
                              hipStream_t stream) {
    const float* nodes = (const float*)d_in[0];
    float* out = (float*)d_out;

    unsigned* cnt = (unsigned*)d_ws;
    short* h = (short*)d_ws + H_OFF_SHORTS;
    const size_t list_off_bytes = 16 + H_ELEMS * sizeof(short);
    unsigned* list = (unsigned*)((char*)d_ws + list_off_bytes);
    const size_t cap_sz = (ws_size > list_off_bytes + 16)
                              ? (ws_size - list_off_bytes) / sizeof(unsigned) : 0;
    const unsigned cap = (unsigned)(cap_sz > (1u << 22) ? (1u << 22) : cap_sz);

    split_kernel<<<(int)((H_ELEMS / 4 + 255) / 256), 256, 0, stream>>>(nodes, h, cnt);

    dim3 grid(TILES * TILES, GROUPS);            // 1024 x 4 = 4096 blocks
    bridge_mfma_kernel<<<grid, 256, 0, stream>>>(h, out, cnt, list, cap);

    fixup_kernel<<<512, 256, 0, stream>>>(nodes, out, cnt, list, cap);
}